// Round 1
// baseline (3502.551 us; speedup 1.0000x reference)
//
#include <hip/hip_runtime.h>

#define N_NODES 100000
#define N_EDGES 1600000
#define F_IN 17
#define H 128
#define K_TYPES 6
#define MD 12
#define OUT_F 150
#define EPSL 1e-5f

// ---------------- aggregation 1: agg1[dst] += x[src], deg[dst] += 1 ----------------
__global__ __launch_bounds__(256) void k_scatter1(const float* __restrict__ x,
                                                  const int* __restrict__ ei,
                                                  float* __restrict__ agg1,
                                                  float* __restrict__ deg) {
    int e = blockIdx.x * 256 + threadIdx.x;
    if (e >= N_EDGES) return;
    int src = ei[e];
    int dst = ei[N_EDGES + e];
    atomicAdd(&deg[dst], 1.0f);
    const float* xr = x + (size_t)src * F_IN;
    float* ar = agg1 + (size_t)dst * F_IN;
#pragma unroll
    for (int f = 0; f < F_IN; ++f) atomicAdd(&ar[f], xr[f]);
}

// ---------------- layer 1: h1 = relu(bn(agg1/deg @ W1l + x @ W1r + b1)) ----------------
__global__ __launch_bounds__(128) void k_layer1(const float* __restrict__ x,
                                                const float* __restrict__ agg1,
                                                const float* __restrict__ deg,
                                                const float* __restrict__ W1l,
                                                const float* __restrict__ W1r,
                                                const float* __restrict__ b1,
                                                const float* __restrict__ g,
                                                const float* __restrict__ bb,
                                                const float* __restrict__ m,
                                                const float* __restrict__ v,
                                                float* __restrict__ h1) {
    int n = blockIdx.x;
    int f = threadIdx.x;
    __shared__ float xs[F_IN], as[F_IN];
    if (f < F_IN) {
        float inv = 1.0f / fmaxf(deg[n], 1.0f);
        xs[f] = x[(size_t)n * F_IN + f];
        as[f] = agg1[(size_t)n * F_IN + f] * inv;
    }
    __syncthreads();
    float acc = b1[f];
#pragma unroll
    for (int i = 0; i < F_IN; ++i)
        acc += as[i] * W1l[i * H + f] + xs[i] * W1r[i * H + f];
    float y = (acc - m[f]) * rsqrtf(v[f] + EPSL) * g[f] + bb[f];
    h1[(size_t)n * H + f] = fmaxf(y, 0.0f);
}

// ---------------- aggregation 2: agg2[dst][f] += h1[src][f] ----------------
__global__ __launch_bounds__(256) void k_scatter2(const float* __restrict__ h1,
                                                  const int* __restrict__ ei,
                                                  float* __restrict__ agg2) {
    long tid = (long)blockIdx.x * 256 + threadIdx.x;
    int e = (int)(tid >> 7);
    int f = (int)(tid & 127);
    int src = ei[e];
    int dst = ei[N_EDGES + e];
    atomicAdd(&agg2[(size_t)dst * H + f], h1[(size_t)src * H + f]);
}

// ---------------- layer 2: h = relu(bn(agg2/deg @ W2l + h1 @ W2r + b2)) ----------------
// 32 nodes per block, 256 threads, 16 outputs per thread
__global__ __launch_bounds__(256) void k_layer2(const float* __restrict__ h1,
                                                const float* __restrict__ agg2,
                                                const float* __restrict__ deg,
                                                const float* __restrict__ W2l,
                                                const float* __restrict__ W2r,
                                                const float* __restrict__ b2,
                                                const float* __restrict__ g,
                                                const float* __restrict__ bb,
                                                const float* __restrict__ m,
                                                const float* __restrict__ v,
                                                float* __restrict__ h) {
    __shared__ float xs[32][2 * H + 1];  // [r][0:128]=agg2/deg, [r][128:256]=h1
    int t = threadIdx.x;
    int n0 = blockIdx.x * 32;
    for (int idx = t; idx < 32 * H; idx += 256) {
        int r = idx >> 7, f = idx & 127;
        int n = n0 + r;
        float inv = 1.0f / fmaxf(deg[n], 1.0f);
        xs[r][f] = agg2[(size_t)n * H + f] * inv;
        xs[r][H + f] = h1[(size_t)n * H + f];
    }
    __syncthreads();
    int c = t & 127;
    int r0 = t >> 7;  // 0 or 1 -> rows r0*16 .. r0*16+15
    float acc[16];
#pragma unroll
    for (int j = 0; j < 16; ++j) acc[j] = 0.f;
    for (int k = 0; k < H; ++k) {
        float wl = W2l[k * H + c];
        float wr = W2r[k * H + c];
#pragma unroll
        for (int j = 0; j < 16; ++j) {
            int r = r0 * 16 + j;
            acc[j] += xs[r][k] * wl + xs[r][H + k] * wr;
        }
    }
    float bi = b2[c];
    float sc = rsqrtf(v[c] + EPSL) * g[c];
    float mm = m[c], be = bb[c];
#pragma unroll
    for (int j = 0; j < 16; ++j) {
        int n = n0 + r0 * 16 + j;
        float y = (acc[j] + bi - mm) * sc + be;
        h[(size_t)n * H + c] = fmaxf(y, 0.f);
    }
}

// ---------------- heads: count head + 6 coord heads, 32 nodes per block ----------------
__global__ __launch_bounds__(256) void k_heads(
    const float* __restrict__ h,
    const float* __restrict__ cntW1, const float* __restrict__ cntb1,
    const float* __restrict__ cbg, const float* __restrict__ cbb,
    const float* __restrict__ cbm, const float* __restrict__ cbv,
    const float* __restrict__ cntW2, const float* __restrict__ cntb2,
    const float* __restrict__ chW1, const float* __restrict__ chb1,
    const float* __restrict__ c1g, const float* __restrict__ c1b,
    const float* __restrict__ c1m, const float* __restrict__ c1v,
    const float* __restrict__ chW2, const float* __restrict__ chb2,
    const float* __restrict__ c2g, const float* __restrict__ c2b,
    const float* __restrict__ c2m, const float* __restrict__ c2v,
    const float* __restrict__ chW3, const float* __restrict__ chb3,
    float* __restrict__ out) {
    __shared__ float hs[32][H + 1];
    __shared__ float z1[32][H + 1];
    __shared__ float z2[32][64 + 1];
    int t = threadIdx.x;
    int n0 = blockIdx.x * 32;

    for (int idx = t; idx < 32 * H; idx += 256) {
        int r = idx >> 7, f = idx & 127;
        hs[r][f] = h[(size_t)(n0 + r) * H + f];
    }
    __syncthreads();

    // count head hidden: c1 = bn(relu(h @ cntW1 + b)) -> z2 buffer (32x64, K=128)
    {
        int c = t & 63, r0 = t >> 6;  // r0 in 0..3 -> rows r0*8..r0*8+7
        float acc[8];
#pragma unroll
        for (int j = 0; j < 8; ++j) acc[j] = 0.f;
        for (int k = 0; k < H; ++k) {
            float w = cntW1[k * 64 + c];
#pragma unroll
            for (int j = 0; j < 8; ++j) acc[j] += hs[r0 * 8 + j][k] * w;
        }
        float bi = cntb1[c];
        float sc = rsqrtf(cbv[c] + EPSL) * cbg[c];
        float mm = cbm[c], be = cbb[c];
#pragma unroll
        for (int j = 0; j < 8; ++j) {
            float y = fmaxf(acc[j] + bi, 0.f);
            z2[r0 * 8 + j][c] = (y - mm) * sc + be;
        }
    }
    __syncthreads();
    // counts = z2 @ cntW2 + b2 -> out[:, 0:6]  (32x6, K=64)
    for (int idx = t; idx < 32 * K_TYPES; idx += 256) {
        int r = idx / K_TYPES, c = idx % K_TYPES;
        float acc = cntb2[c];
        for (int p = 0; p < 64; ++p) acc += z2[r][p] * cntW2[p * K_TYPES + c];
        out[(size_t)(n0 + r) * OUT_F + c] = acc;
    }
    // (no sync needed here: next stage writes z1 only; the sync after it
    //  guarantees all counts-readers of z2 are done before z2 is rewritten)

    for (int k = 0; k < K_TYPES; ++k) {
        // stage A: z1 = bn(relu(hs @ W1 + b1))   (32x128, K=128)
        {
            int c = t & 127, r0 = t >> 7;
            float acc[16];
#pragma unroll
            for (int j = 0; j < 16; ++j) acc[j] = 0.f;
            const float* W1 = chW1 + (size_t)k * H * 128;
            for (int kk = 0; kk < H; ++kk) {
                float w = W1[kk * 128 + c];
#pragma unroll
                for (int j = 0; j < 16; ++j) acc[j] += hs[r0 * 16 + j][kk] * w;
            }
            int ci = k * 128 + c;
            float bi = chb1[ci];
            float sc = rsqrtf(c1v[ci] + EPSL) * c1g[ci];
            float mm = c1m[ci], be = c1b[ci];
#pragma unroll
            for (int j = 0; j < 16; ++j) {
                float y = fmaxf(acc[j] + bi, 0.f);
                z1[r0 * 16 + j][c] = (y - mm) * sc + be;
            }
        }
        __syncthreads();
        // stage B: z2 = bn(relu(z1 @ W2 + b2))   (32x64, K=128)
        {
            int c = t & 63, r0 = t >> 6;
            float acc[8];
#pragma unroll
            for (int j = 0; j < 8; ++j) acc[j] = 0.f;
            const float* W2 = chW2 + (size_t)k * H * 64;
            for (int kk = 0; kk < H; ++kk) {
                float w = W2[kk * 64 + c];
#pragma unroll
                for (int j = 0; j < 8; ++j) acc[j] += z1[r0 * 8 + j][kk] * w;
            }
            int ci = k * 64 + c;
            float bi = chb2[ci];
            float sc = rsqrtf(c2v[ci] + EPSL) * c2g[ci];
            float mm = c2m[ci], be = c2b[ci];
#pragma unroll
            for (int j = 0; j < 8; ++j) {
                float y = fmaxf(acc[j] + bi, 0.f);
                z2[r0 * 8 + j][c] = (y - mm) * sc + be;
            }
        }
        __syncthreads();
        // stage C: out = sigmoid(z2 @ W3 + b3)   (32x24, K=64)
        {
            const float* W3 = chW3 + (size_t)k * 64 * (MD * 2);
            for (int idx = t; idx < 32 * (MD * 2); idx += 256) {
                int r = idx / (MD * 2), c = idx % (MD * 2);
                float acc = chb3[k * (MD * 2) + c];
                for (int p = 0; p < 64; ++p) acc += z2[r][p] * W3[p * (MD * 2) + c];
                out[(size_t)(n0 + r) * OUT_F + K_TYPES + k * (MD * 2) + c] =
                    1.f / (1.f + expf(-acc));
            }
        }
        __syncthreads();
    }
}

extern "C" void kernel_launch(void* const* d_in, const int* in_sizes, int n_in,
                              void* d_out, int out_size, void* d_ws, size_t ws_size,
                              hipStream_t stream) {
    const float* x = (const float*)d_in[0];
    const int* ei = (const int*)d_in[1];
    const float* W1l = (const float*)d_in[2];
    const float* W1r = (const float*)d_in[3];
    const float* b1 = (const float*)d_in[4];
    const float* bn1_g = (const float*)d_in[5];
    const float* bn1_b = (const float*)d_in[6];
    const float* bn1_m = (const float*)d_in[7];
    const float* bn1_v = (const float*)d_in[8];
    const float* W2l = (const float*)d_in[9];
    const float* W2r = (const float*)d_in[10];
    const float* b2 = (const float*)d_in[11];
    const float* bn2_g = (const float*)d_in[12];
    const float* bn2_b = (const float*)d_in[13];
    const float* bn2_m = (const float*)d_in[14];
    const float* bn2_v = (const float*)d_in[15];
    const float* cnt_W1 = (const float*)d_in[16];
    const float* cnt_b1 = (const float*)d_in[17];
    const float* cnt_bn_g = (const float*)d_in[18];
    const float* cnt_bn_b = (const float*)d_in[19];
    const float* cnt_bn_m = (const float*)d_in[20];
    const float* cnt_bn_v = (const float*)d_in[21];
    const float* cnt_W2 = (const float*)d_in[22];
    const float* cnt_b2 = (const float*)d_in[23];
    const float* ch_W1 = (const float*)d_in[24];
    const float* ch_b1 = (const float*)d_in[25];
    const float* ch_bn1_g = (const float*)d_in[26];
    const float* ch_bn1_b = (const float*)d_in[27];
    const float* ch_bn1_m = (const float*)d_in[28];
    const float* ch_bn1_v = (const float*)d_in[29];
    const float* ch_W2 = (const float*)d_in[30];
    const float* ch_b2 = (const float*)d_in[31];
    const float* ch_bn2_g = (const float*)d_in[32];
    const float* ch_bn2_b = (const float*)d_in[33];
    const float* ch_bn2_m = (const float*)d_in[34];
    const float* ch_bn2_v = (const float*)d_in[35];
    const float* ch_W3 = (const float*)d_in[36];
    const float* ch_b3 = (const float*)d_in[37];

    float* out = (float*)d_out;

    // workspace layout (floats): [deg N | agg1 N*17 | agg2 N*128 | h1 N*128 | h N*128]
    float* ws = (float*)d_ws;
    float* deg = ws;
    float* agg1 = deg + N_NODES;
    float* agg2 = agg1 + (size_t)N_NODES * F_IN;
    float* h1 = agg2 + (size_t)N_NODES * H;
    float* h = h1 + (size_t)N_NODES * H;

    // zero the accumulators (deg, agg1, agg2 are contiguous)
    size_t zero_bytes = (size_t)N_NODES * (1 + F_IN + H) * sizeof(float);
    hipMemsetAsync(d_ws, 0, zero_bytes, stream);

    k_scatter1<<<N_EDGES / 256, 256, 0, stream>>>(x, ei, agg1, deg);
    k_layer1<<<N_NODES, 128, 0, stream>>>(x, agg1, deg, W1l, W1r, b1,
                                          bn1_g, bn1_b, bn1_m, bn1_v, h1);
    k_scatter2<<<(long)N_EDGES * H / 256, 256, 0, stream>>>(h1, ei, agg2);
    k_layer2<<<N_NODES / 32, 256, 0, stream>>>(h1, agg2, deg, W2l, W2r, b2,
                                               bn2_g, bn2_b, bn2_m, bn2_v, h);
    k_heads<<<N_NODES / 32, 256, 0, stream>>>(
        h, cnt_W1, cnt_b1, cnt_bn_g, cnt_bn_b, cnt_bn_m, cnt_bn_v, cnt_W2, cnt_b2,
        ch_W1, ch_b1, ch_bn1_g, ch_bn1_b, ch_bn1_m, ch_bn1_v,
        ch_W2, ch_b2, ch_bn2_g, ch_bn2_b, ch_bn2_m, ch_bn2_v,
        ch_W3, ch_b3, out);
}

// Round 2
// 1785.763 us; speedup vs baseline: 1.9614x; 1.9614x over previous
//
#include <hip/hip_runtime.h>

#define N_NODES 100000
#define N_EDGES 1600000
#define F_IN 17
#define H 128
#define K_TYPES 6
#define MD 12
#define OUT_F 150
#define EPSL 1e-5f

#define SCAN_BLOCKS 391  // ceil(100000/256)

// ---------- CSR build: histogram ----------
__global__ __launch_bounds__(256) void k_hist(const int* __restrict__ ei,
                                              int* __restrict__ cnt) {
    int e = blockIdx.x * 256 + threadIdx.x;
    int dst = ei[N_EDGES + e];
    atomicAdd(&cnt[dst], 1);
}

// ---------- CSR build: scan stage 1 (per-block exclusive scan + block sums) ----------
__global__ __launch_bounds__(256) void k_scan1(const int* __restrict__ cnt,
                                               int* __restrict__ rowstart,
                                               int* __restrict__ blocksums) {
    __shared__ int s[256];
    int tid = threadIdx.x;
    int i = blockIdx.x * 256 + tid;
    int v = (i < N_NODES) ? cnt[i] : 0;
    s[tid] = v;
    __syncthreads();
    for (int off = 1; off < 256; off <<= 1) {
        int t = (tid >= off) ? s[tid - off] : 0;
        __syncthreads();
        s[tid] += t;
        __syncthreads();
    }
    if (i < N_NODES) rowstart[i] = s[tid] - v;  // exclusive
    if (tid == 255) blocksums[blockIdx.x] = s[255];
}

// ---------- CSR build: scan stage 2 (scan the 391 block sums, one block) ----------
__global__ __launch_bounds__(512) void k_scan2(int* __restrict__ blocksums) {
    __shared__ int s[512];
    int t = threadIdx.x;
    int v0 = (t < SCAN_BLOCKS) ? blocksums[t] : 0;
    s[t] = v0;
    __syncthreads();
    for (int off = 1; off < 512; off <<= 1) {
        int tv = (t >= off) ? s[t - off] : 0;
        __syncthreads();
        s[t] += tv;
        __syncthreads();
    }
    if (t < SCAN_BLOCKS) blocksums[t] = s[t] - v0;  // exclusive
}

// ---------- CSR build: scan stage 3 (add block offsets; init cursor) ----------
__global__ __launch_bounds__(256) void k_scan3(int* __restrict__ rowstart,
                                               const int* __restrict__ blocksums,
                                               int* __restrict__ cursor) {
    int i = blockIdx.x * 256 + threadIdx.x;
    if (i < N_NODES) {
        int r = rowstart[i] + blocksums[blockIdx.x];
        rowstart[i] = r;
        cursor[i] = r;
    }
}

// ---------- CSR build: fill sorted src list ----------
__global__ __launch_bounds__(256) void k_fill(const int* __restrict__ ei,
                                              int* __restrict__ cursor,
                                              int* __restrict__ sorted_src) {
    int e = blockIdx.x * 256 + threadIdx.x;
    int src = ei[e];
    int dst = ei[N_EDGES + e];
    int pos = atomicAdd(&cursor[dst], 1);
    sorted_src[pos] = src;
}

// ---------- fused agg1 + layer1: one wave per node, 4 nodes/block ----------
__global__ __launch_bounds__(256) void k_agg1_layer1(
    const float* __restrict__ x, const int* __restrict__ rowstart,
    const int* __restrict__ cnt, const int* __restrict__ sorted_src,
    const float* __restrict__ W1l, const float* __restrict__ W1r,
    const float* __restrict__ b1,
    const float* __restrict__ g, const float* __restrict__ bb,
    const float* __restrict__ m, const float* __restrict__ v,
    float* __restrict__ h1) {
    int wave = threadIdx.x >> 6;
    int lane = threadIdx.x & 63;
    int n = blockIdx.x * 4 + wave;
    __shared__ float as[4][F_IN], xs[4][F_IN];

    int rs = rowstart[n];
    int d = cnt[n];
    if (lane < F_IN) {
        float acc = 0.f;
        for (int j = 0; j < d; ++j) {
            int src = sorted_src[rs + j];
            acc += x[(size_t)src * F_IN + lane];
        }
        float inv = 1.0f / fmaxf((float)d, 1.0f);
        as[wave][lane] = acc * inv;
        xs[wave][lane] = x[(size_t)n * F_IN + lane];
    }
    __syncthreads();

    // lane computes output features lane and lane+64
    float a0 = b1[lane], a1 = b1[lane + 64];
    for (int i = 0; i < F_IN; ++i) {
        float av = as[wave][i], xv = xs[wave][i];
        a0 += av * W1l[i * H + lane] + xv * W1r[i * H + lane];
        a1 += av * W1l[i * H + 64 + lane] + xv * W1r[i * H + 64 + lane];
    }
    int f0 = lane, f1 = lane + 64;
    float y0 = (a0 - m[f0]) * rsqrtf(v[f0] + EPSL) * g[f0] + bb[f0];
    float y1 = (a1 - m[f1]) * rsqrtf(v[f1] + EPSL) * g[f1] + bb[f1];
    h1[(size_t)n * H + f0] = fmaxf(y0, 0.f);
    h1[(size_t)n * H + f1] = fmaxf(y1, 0.f);
}

// ---------- fused agg2 + layer2: 32 nodes/block; wave-per-node gather then tiled GEMM ----------
__global__ __launch_bounds__(256) void k_agg2_layer2(
    const float* __restrict__ h1, const int* __restrict__ rowstart,
    const int* __restrict__ cnt, const int* __restrict__ sorted_src,
    const float* __restrict__ W2l, const float* __restrict__ W2r,
    const float* __restrict__ b2,
    const float* __restrict__ g, const float* __restrict__ bb,
    const float* __restrict__ m, const float* __restrict__ v,
    float* __restrict__ h) {
    __shared__ float xs[32][2 * H + 1];  // [r][0:128]=agg_mean, [r][128:256]=h1 root
    int t = threadIdx.x;
    int wave = t >> 6, lane = t & 63;
    int n0 = blockIdx.x * 32;
    const float2* h1v = (const float2*)h1;

    // gather phase: each wave averages 8 nodes' neighborhoods (float2 per lane)
    for (int q = 0; q < 8; ++q) {
        int r = wave * 8 + q;
        int n = n0 + r;
        int rs = rowstart[n];
        int d = cnt[n];
        float sx = 0.f, sy = 0.f;
        for (int j = 0; j < d; ++j) {
            int src = sorted_src[rs + j];
            float2 vv = h1v[(size_t)src * 64 + lane];
            sx += vv.x;
            sy += vv.y;
        }
        float inv = 1.f / fmaxf((float)d, 1.f);
        xs[r][2 * lane] = sx * inv;
        xs[r][2 * lane + 1] = sy * inv;
        float2 hv = h1v[(size_t)n * 64 + lane];
        xs[r][H + 2 * lane] = hv.x;
        xs[r][H + 2 * lane + 1] = hv.y;
    }
    __syncthreads();

    // GEMM phase: 32x128 output tile, K=128, dual weight matrices
    int c = t & 127;
    int r0 = t >> 7;
    float acc[16];
#pragma unroll
    for (int j = 0; j < 16; ++j) acc[j] = 0.f;
    for (int k = 0; k < H; ++k) {
        float wl = W2l[k * H + c];
        float wr = W2r[k * H + c];
#pragma unroll
        for (int j = 0; j < 16; ++j) {
            int r = r0 * 16 + j;
            acc[j] += xs[r][k] * wl + xs[r][H + k] * wr;
        }
    }
    float bi = b2[c];
    float sc = rsqrtf(v[c] + EPSL) * g[c];
    float mm = m[c], be = bb[c];
#pragma unroll
    for (int j = 0; j < 16; ++j) {
        int n = n0 + r0 * 16 + j;
        float y = (acc[j] + bi - mm) * sc + be;
        h[(size_t)n * H + c] = fmaxf(y, 0.f);
    }
}

// ---------------- heads: count head + 6 coord heads, 32 nodes per block ----------------
__global__ __launch_bounds__(256) void k_heads(
    const float* __restrict__ h,
    const float* __restrict__ cntW1, const float* __restrict__ cntb1,
    const float* __restrict__ cbg, const float* __restrict__ cbb,
    const float* __restrict__ cbm, const float* __restrict__ cbv,
    const float* __restrict__ cntW2, const float* __restrict__ cntb2,
    const float* __restrict__ chW1, const float* __restrict__ chb1,
    const float* __restrict__ c1g, const float* __restrict__ c1b,
    const float* __restrict__ c1m, const float* __restrict__ c1v,
    const float* __restrict__ chW2, const float* __restrict__ chb2,
    const float* __restrict__ c2g, const float* __restrict__ c2b,
    const float* __restrict__ c2m, const float* __restrict__ c2v,
    const float* __restrict__ chW3, const float* __restrict__ chb3,
    float* __restrict__ out) {
    __shared__ float hs[32][H + 1];
    __shared__ float z1[32][H + 1];
    __shared__ float z2[32][64 + 1];
    int t = threadIdx.x;
    int n0 = blockIdx.x * 32;

    for (int idx = t; idx < 32 * H; idx += 256) {
        int r = idx >> 7, f = idx & 127;
        hs[r][f] = h[(size_t)(n0 + r) * H + f];
    }
    __syncthreads();

    // count head hidden: z2 = bn(relu(h @ cntW1 + b))   (32x64, K=128)
    {
        int c = t & 63, r0 = t >> 6;
        float acc[8];
#pragma unroll
        for (int j = 0; j < 8; ++j) acc[j] = 0.f;
        for (int k = 0; k < H; ++k) {
            float w = cntW1[k * 64 + c];
#pragma unroll
            for (int j = 0; j < 8; ++j) acc[j] += hs[r0 * 8 + j][k] * w;
        }
        float bi = cntb1[c];
        float sc = rsqrtf(cbv[c] + EPSL) * cbg[c];
        float mm = cbm[c], be = cbb[c];
#pragma unroll
        for (int j = 0; j < 8; ++j) {
            float y = fmaxf(acc[j] + bi, 0.f);
            z2[r0 * 8 + j][c] = (y - mm) * sc + be;
        }
    }
    __syncthreads();
    // counts = z2 @ cntW2 + b2 -> out[:, 0:6]
    for (int idx = t; idx < 32 * K_TYPES; idx += 256) {
        int r = idx / K_TYPES, c = idx % K_TYPES;
        float acc = cntb2[c];
        for (int p = 0; p < 64; ++p) acc += z2[r][p] * cntW2[p * K_TYPES + c];
        out[(size_t)(n0 + r) * OUT_F + c] = acc;
    }

    for (int k = 0; k < K_TYPES; ++k) {
        // stage A: z1 = bn(relu(hs @ W1 + b1))   (32x128, K=128)
        {
            int c = t & 127, r0 = t >> 7;
            float acc[16];
#pragma unroll
            for (int j = 0; j < 16; ++j) acc[j] = 0.f;
            const float* W1 = chW1 + (size_t)k * H * 128;
            for (int kk = 0; kk < H; ++kk) {
                float w = W1[kk * 128 + c];
#pragma unroll
                for (int j = 0; j < 16; ++j) acc[j] += hs[r0 * 16 + j][kk] * w;
            }
            int ci = k * 128 + c;
            float bi = chb1[ci];
            float sc = rsqrtf(c1v[ci] + EPSL) * c1g[ci];
            float mm = c1m[ci], be = c1b[ci];
#pragma unroll
            for (int j = 0; j < 16; ++j) {
                float y = fmaxf(acc[j] + bi, 0.f);
                z1[r0 * 16 + j][c] = (y - mm) * sc + be;
            }
        }
        __syncthreads();
        // stage B: z2 = bn(relu(z1 @ W2 + b2))   (32x64, K=128)
        {
            int c = t & 63, r0 = t >> 6;
            float acc[8];
#pragma unroll
            for (int j = 0; j < 8; ++j) acc[j] = 0.f;
            const float* W2 = chW2 + (size_t)k * H * 64;
            for (int kk = 0; kk < H; ++kk) {
                float w = W2[kk * 64 + c];
#pragma unroll
                for (int j = 0; j < 8; ++j) acc[j] += z1[r0 * 8 + j][kk] * w;
            }
            int ci = k * 64 + c;
            float bi = chb2[ci];
            float sc = rsqrtf(c2v[ci] + EPSL) * c2g[ci];
            float mm = c2m[ci], be = c2b[ci];
#pragma unroll
            for (int j = 0; j < 8; ++j) {
                float y = fmaxf(acc[j] + bi, 0.f);
                z2[r0 * 8 + j][c] = (y - mm) * sc + be;
            }
        }
        __syncthreads();
        // stage C: out = sigmoid(z2 @ W3 + b3)   (32x24, K=64)
        {
            const float* W3 = chW3 + (size_t)k * 64 * (MD * 2);
            for (int idx = t; idx < 32 * (MD * 2); idx += 256) {
                int r = idx / (MD * 2), c = idx % (MD * 2);
                float acc = chb3[k * (MD * 2) + c];
                for (int p = 0; p < 64; ++p) acc += z2[r][p] * W3[p * (MD * 2) + c];
                out[(size_t)(n0 + r) * OUT_F + K_TYPES + k * (MD * 2) + c] =
                    1.f / (1.f + expf(-acc));
            }
        }
        __syncthreads();
    }
}

extern "C" void kernel_launch(void* const* d_in, const int* in_sizes, int n_in,
                              void* d_out, int out_size, void* d_ws, size_t ws_size,
                              hipStream_t stream) {
    const float* x = (const float*)d_in[0];
    const int* ei = (const int*)d_in[1];
    const float* W1l = (const float*)d_in[2];
    const float* W1r = (const float*)d_in[3];
    const float* b1 = (const float*)d_in[4];
    const float* bn1_g = (const float*)d_in[5];
    const float* bn1_b = (const float*)d_in[6];
    const float* bn1_m = (const float*)d_in[7];
    const float* bn1_v = (const float*)d_in[8];
    const float* W2l = (const float*)d_in[9];
    const float* W2r = (const float*)d_in[10];
    const float* b2 = (const float*)d_in[11];
    const float* bn2_g = (const float*)d_in[12];
    const float* bn2_b = (const float*)d_in[13];
    const float* bn2_m = (const float*)d_in[14];
    const float* bn2_v = (const float*)d_in[15];
    const float* cnt_W1 = (const float*)d_in[16];
    const float* cnt_b1 = (const float*)d_in[17];
    const float* cnt_bn_g = (const float*)d_in[18];
    const float* cnt_bn_b = (const float*)d_in[19];
    const float* cnt_bn_m = (const float*)d_in[20];
    const float* cnt_bn_v = (const float*)d_in[21];
    const float* cnt_W2 = (const float*)d_in[22];
    const float* cnt_b2 = (const float*)d_in[23];
    const float* ch_W1 = (const float*)d_in[24];
    const float* ch_b1 = (const float*)d_in[25];
    const float* ch_bn1_g = (const float*)d_in[26];
    const float* ch_bn1_b = (const float*)d_in[27];
    const float* ch_bn1_m = (const float*)d_in[28];
    const float* ch_bn1_v = (const float*)d_in[29];
    const float* ch_W2 = (const float*)d_in[30];
    const float* ch_b2 = (const float*)d_in[31];
    const float* ch_bn2_g = (const float*)d_in[32];
    const float* ch_bn2_b = (const float*)d_in[33];
    const float* ch_bn2_m = (const float*)d_in[34];
    const float* ch_bn2_v = (const float*)d_in[35];
    const float* ch_W3 = (const float*)d_in[36];
    const float* ch_b3 = (const float*)d_in[37];

    float* out = (float*)d_out;

    // workspace layout:
    // ints:  cnt[N] | rowstart[N] | cursor[N] | blocksums[512] | sorted_src[E]
    // floats: h1[N*H] | h[N*H]
    int* cnt = (int*)d_ws;
    int* rowstart = cnt + N_NODES;
    int* cursor = rowstart + N_NODES;
    int* blocksums = cursor + N_NODES;
    int* sorted_src = blocksums + 512;
    float* h1 = (float*)(sorted_src + N_EDGES);
    float* h = h1 + (size_t)N_NODES * H;

    // zero only the histogram
    hipMemsetAsync(cnt, 0, N_NODES * sizeof(int), stream);

    k_hist<<<N_EDGES / 256, 256, 0, stream>>>(ei, cnt);
    k_scan1<<<SCAN_BLOCKS, 256, 0, stream>>>(cnt, rowstart, blocksums);
    k_scan2<<<1, 512, 0, stream>>>(blocksums);
    k_scan3<<<SCAN_BLOCKS, 256, 0, stream>>>(rowstart, blocksums, cursor);
    k_fill<<<N_EDGES / 256, 256, 0, stream>>>(ei, cursor, sorted_src);

    k_agg1_layer1<<<N_NODES / 4, 256, 0, stream>>>(x, rowstart, cnt, sorted_src,
                                                   W1l, W1r, b1,
                                                   bn1_g, bn1_b, bn1_m, bn1_v, h1);
    k_agg2_layer2<<<N_NODES / 32, 256, 0, stream>>>(h1, rowstart, cnt, sorted_src,
                                                    W2l, W2r, b2,
                                                    bn2_g, bn2_b, bn2_m, bn2_v, h);
    k_heads<<<N_NODES / 32, 256, 0, stream>>>(
        h, cnt_W1, cnt_b1, cnt_bn_g, cnt_bn_b, cnt_bn_m, cnt_bn_v, cnt_W2, cnt_b2,
        ch_W1, ch_b1, ch_bn1_g, ch_bn1_b, ch_bn1_m, ch_bn1_v,
        ch_W2, ch_b2, ch_bn2_g, ch_bn2_b, ch_bn2_m, ch_bn2_v,
        ch_W3, ch_b3, out);
}

// Round 3
// 968.208 us; speedup vs baseline: 3.6176x; 1.8444x over previous
//
#include <hip/hip_runtime.h>

#define N_NODES 100000
#define N_EDGES 1600000
#define F_IN 17
#define H 128
#define K_TYPES 6
#define MD 12
#define OUT_F 150
#define EPSL 1e-5f

#define SCAN_BLOCKS 391  // ceil(100000/256)

#define LDH 136  // LDS row stride (bf16) for 128-col tiles: 272 B rows -> bank-friendly
#define LDZ 72   // LDS row stride (bf16) for 64-col tiles: 144 B rows

typedef __attribute__((ext_vector_type(8))) short bf16x8;
typedef __attribute__((ext_vector_type(4))) float f32x4;

static __device__ __forceinline__ short f2bf(float f) {
    union { float f; unsigned u; } v;
    v.f = f;
    unsigned r = (v.u + 0x7FFF + ((v.u >> 16) & 1)) >> 16;  // RNE
    return (short)r;
}

// ---------- CSR build: histogram ----------
__global__ __launch_bounds__(256) void k_hist(const int* __restrict__ ei,
                                              int* __restrict__ cnt) {
    int e = blockIdx.x * 256 + threadIdx.x;
    int dst = ei[N_EDGES + e];
    atomicAdd(&cnt[dst], 1);
}

// ---------- CSR build: scan stage 1 ----------
__global__ __launch_bounds__(256) void k_scan1(const int* __restrict__ cnt,
                                               int* __restrict__ rowstart,
                                               int* __restrict__ blocksums) {
    __shared__ int s[256];
    int tid = threadIdx.x;
    int i = blockIdx.x * 256 + tid;
    int v = (i < N_NODES) ? cnt[i] : 0;
    s[tid] = v;
    __syncthreads();
    for (int off = 1; off < 256; off <<= 1) {
        int t = (tid >= off) ? s[tid - off] : 0;
        __syncthreads();
        s[tid] += t;
        __syncthreads();
    }
    if (i < N_NODES) rowstart[i] = s[tid] - v;
    if (tid == 255) blocksums[blockIdx.x] = s[255];
}

// ---------- CSR build: scan stage 2 ----------
__global__ __launch_bounds__(512) void k_scan2(int* __restrict__ blocksums) {
    __shared__ int s[512];
    int t = threadIdx.x;
    int v0 = (t < SCAN_BLOCKS) ? blocksums[t] : 0;
    s[t] = v0;
    __syncthreads();
    for (int off = 1; off < 512; off <<= 1) {
        int tv = (t >= off) ? s[t - off] : 0;
        __syncthreads();
        s[t] += tv;
        __syncthreads();
    }
    if (t < SCAN_BLOCKS) blocksums[t] = s[t] - v0;
}

// ---------- CSR build: scan stage 3 ----------
__global__ __launch_bounds__(256) void k_scan3(int* __restrict__ rowstart,
                                               const int* __restrict__ blocksums,
                                               int* __restrict__ cursor) {
    int i = blockIdx.x * 256 + threadIdx.x;
    if (i < N_NODES) {
        int r = rowstart[i] + blocksums[blockIdx.x];
        rowstart[i] = r;
        cursor[i] = r;
    }
}

// ---------- CSR build: fill ----------
__global__ __launch_bounds__(256) void k_fill(const int* __restrict__ ei,
                                              int* __restrict__ cursor,
                                              int* __restrict__ sorted_src) {
    int e = blockIdx.x * 256 + threadIdx.x;
    int src = ei[e];
    int dst = ei[N_EDGES + e];
    int pos = atomicAdd(&cursor[dst], 1);
    sorted_src[pos] = src;
}

// ---------- prep: BN-fold + transpose + bf16-convert head weights ----------
__global__ __launch_bounds__(256) void k_prep(
    const float* __restrict__ ch_W1, const float* __restrict__ ch_W2,
    const float* __restrict__ ch_W3,
    const float* __restrict__ c1g, const float* __restrict__ c1b,
    const float* __restrict__ c1m, const float* __restrict__ c1v,
    const float* __restrict__ c2g, const float* __restrict__ c2b,
    const float* __restrict__ c2m, const float* __restrict__ c2v,
    const float* __restrict__ cnt_W1, const float* __restrict__ cnt_W2,
    const float* __restrict__ cbg, const float* __restrict__ cbb,
    const float* __restrict__ cbm, const float* __restrict__ cbv,
    const float* __restrict__ ch_b2, const float* __restrict__ ch_b3,
    const float* __restrict__ cnt_b2,
    short* __restrict__ W1t, short* __restrict__ W2ft, short* __restrict__ W3ft,
    short* __restrict__ cntW1t, short* __restrict__ cntW2ft,
    float* __restrict__ b2f, float* __restrict__ b3f, float* __restrict__ cntb2f) {
    int i = blockIdx.x * 256 + threadIdx.x;
    if (i < 98304) {  // W1t[k][o<128][d<128] <- ch_W1[k][d][o]
        int k = i >> 14, rem = i & 16383, o = rem >> 7, d = rem & 127;
        W1t[i] = f2bf(ch_W1[(k << 14) + (d << 7) + o]);
    } else if ((i -= 98304) < 49152) {  // W2ft[k][o<64][d<128] = A1[k][d]*ch_W2[k][d][o]
        int k = i >> 13, rem = i & 8191, o = rem >> 7, d = rem & 127;
        int ci = (k << 7) + d;
        float A1 = c1g[ci] * rsqrtf(c1v[ci] + EPSL);
        W2ft[i] = f2bf(ch_W2[(k << 13) + (d << 6) + o] * A1);
    } else if ((i -= 49152) < 12288) {  // W3ft[k][o<32][d<64], zero-pad o>=24
        int k = i >> 11, rem = i & 2047, o = rem >> 6, d = rem & 63;
        float val = 0.f;
        if (o < 24) {
            int ci = (k << 6) + d;
            float A2 = c2g[ci] * rsqrtf(c2v[ci] + EPSL);
            val = ch_W3[k * 1536 + d * 24 + o] * A2;
        }
        W3ft[i] = f2bf(val);
    } else if ((i -= 12288) < 8192) {  // cntW1t[o<64][d<128]
        int o = i >> 7, d = i & 127;
        cntW1t[i] = f2bf(cnt_W1[(d << 6) + o]);
    } else if ((i -= 8192) < 1024) {  // cntW2ft[o<16][d<64], zero-pad o>=6
        int o = i >> 6, d = i & 63;
        float val = 0.f;
        if (o < 6) val = cnt_W2[d * 6 + o] * (cbg[d] * rsqrtf(cbv[d] + EPSL));
        cntW2ft[i] = f2bf(val);
    } else if ((i -= 1024) < 384) {  // b2f[k][o<64]
        int k = i >> 6, o = i & 63;
        float s = ch_b2[i];
        for (int d = 0; d < 128; ++d) {
            int ci = (k << 7) + d;
            float A1 = c1g[ci] * rsqrtf(c1v[ci] + EPSL);
            float B1 = c1b[ci] - c1m[ci] * A1;
            s += B1 * ch_W2[(k << 13) + (d << 6) + o];
        }
        b2f[i] = s;
    } else if ((i -= 384) < 144) {  // b3f[k][o<24]
        int k = i / 24, o = i - k * 24;
        float s = ch_b3[i];
        for (int d = 0; d < 64; ++d) {
            int ci = (k << 6) + d;
            float A2 = c2g[ci] * rsqrtf(c2v[ci] + EPSL);
            float B2 = c2b[ci] - c2m[ci] * A2;
            s += B2 * ch_W3[k * 1536 + d * 24 + o];
        }
        b3f[i] = s;
    } else if ((i -= 144) < 6) {  // cntb2f[o<6]
        float s = cnt_b2[i];
        for (int d = 0; d < 64; ++d) {
            float Ac = cbg[d] * rsqrtf(cbv[d] + EPSL);
            float Bc = cbb[d] - cbm[d] * Ac;
            s += Bc * cnt_W2[d * 6 + i];
        }
        cntb2f[i] = s;
    }
}

// ---------- fused agg1 + layer1 ----------
__global__ __launch_bounds__(256) void k_agg1_layer1(
    const float* __restrict__ x, const int* __restrict__ rowstart,
    const int* __restrict__ cnt, const int* __restrict__ sorted_src,
    const float* __restrict__ W1l, const float* __restrict__ W1r,
    const float* __restrict__ b1,
    const float* __restrict__ g, const float* __restrict__ bb,
    const float* __restrict__ m, const float* __restrict__ v,
    float* __restrict__ h1) {
    int wave = threadIdx.x >> 6;
    int lane = threadIdx.x & 63;
    int n = blockIdx.x * 4 + wave;
    __shared__ float as[4][F_IN], xs[4][F_IN];

    int rs = rowstart[n];
    int d = cnt[n];
    if (lane < F_IN) {
        float acc = 0.f;
        for (int j = 0; j < d; ++j) {
            int src = sorted_src[rs + j];
            acc += x[(size_t)src * F_IN + lane];
        }
        float inv = 1.0f / fmaxf((float)d, 1.0f);
        as[wave][lane] = acc * inv;
        xs[wave][lane] = x[(size_t)n * F_IN + lane];
    }
    __syncthreads();

    float a0 = b1[lane], a1 = b1[lane + 64];
    for (int i = 0; i < F_IN; ++i) {
        float av = as[wave][i], xv = xs[wave][i];
        a0 += av * W1l[i * H + lane] + xv * W1r[i * H + lane];
        a1 += av * W1l[i * H + 64 + lane] + xv * W1r[i * H + 64 + lane];
    }
    int f0 = lane, f1 = lane + 64;
    float y0 = (a0 - m[f0]) * rsqrtf(v[f0] + EPSL) * g[f0] + bb[f0];
    float y1 = (a1 - m[f1]) * rsqrtf(v[f1] + EPSL) * g[f1] + bb[f1];
    h1[(size_t)n * H + f0] = fmaxf(y0, 0.f);
    h1[(size_t)n * H + f1] = fmaxf(y1, 0.f);
}

// ---------- fused agg2 + layer2 (writes h as bf16) ----------
__global__ __launch_bounds__(256) void k_agg2_layer2(
    const float* __restrict__ h1, const int* __restrict__ rowstart,
    const int* __restrict__ cnt, const int* __restrict__ sorted_src,
    const float* __restrict__ W2l, const float* __restrict__ W2r,
    const float* __restrict__ b2,
    const float* __restrict__ g, const float* __restrict__ bb,
    const float* __restrict__ m, const float* __restrict__ v,
    short* __restrict__ hb) {
    __shared__ float xs[32][2 * H + 1];
    int t = threadIdx.x;
    int wave = t >> 6, lane = t & 63;
    int n0 = blockIdx.x * 32;
    const float2* h1v = (const float2*)h1;

    for (int q = 0; q < 8; ++q) {
        int r = wave * 8 + q;
        int n = n0 + r;
        int rs = rowstart[n];
        int d = cnt[n];
        float sx = 0.f, sy = 0.f;
        for (int j = 0; j < d; ++j) {
            int src = sorted_src[rs + j];
            float2 vv = h1v[(size_t)src * 64 + lane];
            sx += vv.x;
            sy += vv.y;
        }
        float inv = 1.f / fmaxf((float)d, 1.f);
        xs[r][2 * lane] = sx * inv;
        xs[r][2 * lane + 1] = sy * inv;
        float2 hv = h1v[(size_t)n * 64 + lane];
        xs[r][H + 2 * lane] = hv.x;
        xs[r][H + 2 * lane + 1] = hv.y;
    }
    __syncthreads();

    int c = t & 127;
    int r0 = t >> 7;
    float acc[16];
#pragma unroll
    for (int j = 0; j < 16; ++j) acc[j] = 0.f;
    for (int k = 0; k < H; ++k) {
        float wl = W2l[k * H + c];
        float wr = W2r[k * H + c];
#pragma unroll
        for (int j = 0; j < 16; ++j) {
            int r = r0 * 16 + j;
            acc[j] += xs[r][k] * wl + xs[r][H + k] * wr;
        }
    }
    float bi = b2[c];
    float sc = rsqrtf(v[c] + EPSL) * g[c];
    float mm = m[c], be = bb[c];
#pragma unroll
    for (int j = 0; j < 16; ++j) {
        int n = n0 + r0 * 16 + j;
        float y = (acc[j] + bi - mm) * sc + be;
        hb[(size_t)n * H + c] = f2bf(fmaxf(y, 0.f));
    }
}

// ---------- heads via MFMA: 64 nodes/block, 4 waves ----------
__global__ __launch_bounds__(256) void k_heads_mfma(
    const short* __restrict__ hb,
    const float* __restrict__ cntb1, const float* __restrict__ ch_b1,
    const short* __restrict__ W1t, const short* __restrict__ W2ft,
    const short* __restrict__ W3ft, const short* __restrict__ cntW1t,
    const short* __restrict__ cntW2ft,
    const float* __restrict__ b2f, const float* __restrict__ b3f,
    const float* __restrict__ cntb2f,
    float* __restrict__ out) {
    __shared__ short hs[64 * LDH];
    __shared__ short z1[64 * LDH];
    __shared__ short z2[64 * LDZ];
    __shared__ short wst[64 * LDH];

    int t = threadIdx.x;
    int lane = t & 63, w = t >> 6;
    int lr = lane & 15, lk = lane >> 4;
    int n0 = blockIdx.x * 64;

    // stage h tile (rows clamped; stores masked later)
#pragma unroll
    for (int it = 0; it < 4; ++it) {
        int idx = t * 8 + it * 2048;
        int r = idx >> 7, c = idx & 127;
        int n = n0 + r;
        if (n > N_NODES - 1) n = N_NODES - 1;
        *(int4*)&hs[r * LDH + c] = *(const int4*)&hb[(size_t)n * 128 + c];
    }
    __syncthreads();

    // ===== count head =====
#pragma unroll
    for (int it = 0; it < 4; ++it) {
        int idx = t * 8 + it * 2048;
        int r = idx >> 7, c = idx & 127;
        *(int4*)&wst[r * LDH + c] = *(const int4*)&cntW1t[idx];
    }
    __syncthreads();
    {
        f32x4 acc[4] = {};
#pragma unroll
        for (int ks = 0; ks < 4; ++ks) {
            bf16x8 a = *(bf16x8*)&hs[(16 * w + lr) * LDH + 32 * ks + lk * 8];
#pragma unroll
            for (int ct = 0; ct < 4; ++ct) {
                bf16x8 b = *(bf16x8*)&wst[(16 * ct + lr) * LDH + 32 * ks + lk * 8];
                acc[ct] = __builtin_amdgcn_mfma_f32_16x16x32_bf16(a, b, acc[ct], 0, 0, 0);
            }
        }
        __syncthreads();  // wst reads done
#pragma unroll
        for (int ct = 0; ct < 4; ++ct) {
            int c = 16 * ct + lr;
            float bi = cntb1[c];
#pragma unroll
            for (int j = 0; j < 4; ++j) {
                int r = 16 * w + lk * 4 + j;
                z2[r * LDZ + c] = f2bf(fmaxf(acc[ct][j] + bi, 0.f));
            }
        }
    }
    {
        int idx = t * 8;
        if (idx < 16 * 64) {
            int r = idx >> 6, c = idx & 63;
            *(int4*)&wst[r * LDZ + c] = *(const int4*)&cntW2ft[idx];
        }
    }
    __syncthreads();
    {
        f32x4 acc = {};
#pragma unroll
        for (int ks = 0; ks < 2; ++ks) {
            bf16x8 a = *(bf16x8*)&z2[(16 * w + lr) * LDZ + 32 * ks + lk * 8];
            bf16x8 b = *(bf16x8*)&wst[lr * LDZ + 32 * ks + lk * 8];
            acc = __builtin_amdgcn_mfma_f32_16x16x32_bf16(a, b, acc, 0, 0, 0);
        }
        if (lr < 6) {
            float bi = cntb2f[lr];
#pragma unroll
            for (int j = 0; j < 4; ++j) {
                int r = 16 * w + lk * 4 + j, n = n0 + r;
                if (n < N_NODES) out[(size_t)n * OUT_F + lr] = acc[j] + bi;
            }
        }
    }
    __syncthreads();

    // ===== coord heads =====
    for (int k = 0; k < K_TYPES; ++k) {
        const short* W1k = W1t + k * 16384;
        // GEMM1: h(64x128) @ W1^T, output cols in two halves of 64
        for (int half = 0; half < 2; ++half) {
#pragma unroll
            for (int it = 0; it < 4; ++it) {
                int idx = t * 8 + it * 2048;
                int r = idx >> 7, c = idx & 127;
                *(int4*)&wst[r * LDH + c] = *(const int4*)&W1k[half * 8192 + idx];
            }
            __syncthreads();
            f32x4 acc[4] = {};
#pragma unroll
            for (int ks = 0; ks < 4; ++ks) {
                bf16x8 a = *(bf16x8*)&hs[(16 * w + lr) * LDH + 32 * ks + lk * 8];
#pragma unroll
                for (int ct = 0; ct < 4; ++ct) {
                    bf16x8 b = *(bf16x8*)&wst[(16 * ct + lr) * LDH + 32 * ks + lk * 8];
                    acc[ct] = __builtin_amdgcn_mfma_f32_16x16x32_bf16(a, b, acc[ct], 0, 0, 0);
                }
            }
            __syncthreads();  // wst reads done
#pragma unroll
            for (int ct = 0; ct < 4; ++ct) {
                int c = 64 * half + 16 * ct + lr;
                float bi = ch_b1[k * 128 + c];
#pragma unroll
                for (int j = 0; j < 4; ++j) {
                    int r = 16 * w + lk * 4 + j;
                    z1[r * LDH + c] = f2bf(fmaxf(acc[ct][j] + bi, 0.f));
                }
            }
        }
        // GEMM2: z1(64x128) @ W2f^T -> z2(64x64)
#pragma unroll
        for (int it = 0; it < 4; ++it) {
            int idx = t * 8 + it * 2048;
            int r = idx >> 7, c = idx & 127;
            *(int4*)&wst[r * LDH + c] = *(const int4*)&W2ft[k * 8192 + idx];
        }
        __syncthreads();  // z1 writes + wst ready
        {
            f32x4 acc[4] = {};
#pragma unroll
            for (int ks = 0; ks < 4; ++ks) {
                bf16x8 a = *(bf16x8*)&z1[(16 * w + lr) * LDH + 32 * ks + lk * 8];
#pragma unroll
                for (int ct = 0; ct < 4; ++ct) {
                    bf16x8 b = *(bf16x8*)&wst[(16 * ct + lr) * LDH + 32 * ks + lk * 8];
                    acc[ct] = __builtin_amdgcn_mfma_f32_16x16x32_bf16(a, b, acc[ct], 0, 0, 0);
                }
            }
            __syncthreads();
#pragma unroll
            for (int ct = 0; ct < 4; ++ct) {
                int c = 16 * ct + lr;
                float bi = b2f[k * 64 + c];
#pragma unroll
                for (int j = 0; j < 4; ++j) {
                    int r = 16 * w + lk * 4 + j;
                    z2[r * LDZ + c] = f2bf(fmaxf(acc[ct][j] + bi, 0.f));
                }
            }
        }
        // GEMM3: z2(64x64) @ W3f^T -> sigmoid -> out
        {
            int idx = t * 8;  // 2048 elements, one shot
            int r = idx >> 6, c = idx & 63;
            *(int4*)&wst[r * LDZ + c] = *(const int4*)&W3ft[k * 2048 + idx];
        }
        __syncthreads();  // z2 writes + wst ready
        {
            f32x4 acc[2] = {};
#pragma unroll
            for (int ks = 0; ks < 2; ++ks) {
                bf16x8 a = *(bf16x8*)&z2[(16 * w + lr) * LDZ + 32 * ks + lk * 8];
#pragma unroll
                for (int ct = 0; ct < 2; ++ct) {
                    bf16x8 b = *(bf16x8*)&wst[(16 * ct + lr) * LDZ + 32 * ks + lk * 8];
                    acc[ct] = __builtin_amdgcn_mfma_f32_16x16x32_bf16(a, b, acc[ct], 0, 0, 0);
                }
            }
#pragma unroll
            for (int ct = 0; ct < 2; ++ct) {
                int c = 16 * ct + lr;
                if (c < 24) {
                    float bi = b3f[k * 24 + c];
#pragma unroll
                    for (int j = 0; j < 4; ++j) {
                        int r = 16 * w + lk * 4 + j, n = n0 + r;
                        if (n < N_NODES)
                            out[(size_t)n * OUT_F + 6 + 24 * k + c] =
                                1.f / (1.f + expf(-(acc[ct][j] + bi)));
                    }
                }
            }
        }
        __syncthreads();  // before next head restages wst
    }
}

extern "C" void kernel_launch(void* const* d_in, const int* in_sizes, int n_in,
                              void* d_out, int out_size, void* d_ws, size_t ws_size,
                              hipStream_t stream) {
    const float* x = (const float*)d_in[0];
    const int* ei = (const int*)d_in[1];
    const float* W1l = (const float*)d_in[2];
    const float* W1r = (const float*)d_in[3];
    const float* b1 = (const float*)d_in[4];
    const float* bn1_g = (const float*)d_in[5];
    const float* bn1_b = (const float*)d_in[6];
    const float* bn1_m = (const float*)d_in[7];
    const float* bn1_v = (const float*)d_in[8];
    const float* W2l = (const float*)d_in[9];
    const float* W2r = (const float*)d_in[10];
    const float* b2 = (const float*)d_in[11];
    const float* bn2_g = (const float*)d_in[12];
    const float* bn2_b = (const float*)d_in[13];
    const float* bn2_m = (const float*)d_in[14];
    const float* bn2_v = (const float*)d_in[15];
    const float* cnt_W1 = (const float*)d_in[16];
    const float* cnt_b1 = (const float*)d_in[17];
    const float* cnt_bn_g = (const float*)d_in[18];
    const float* cnt_bn_b = (const float*)d_in[19];
    const float* cnt_bn_m = (const float*)d_in[20];
    const float* cnt_bn_v = (const float*)d_in[21];
    const float* cnt_W2 = (const float*)d_in[22];
    const float* cnt_b2 = (const float*)d_in[23];
    const float* ch_W1 = (const float*)d_in[24];
    const float* ch_b1 = (const float*)d_in[25];
    const float* ch_bn1_g = (const float*)d_in[26];
    const float* ch_bn1_b = (const float*)d_in[27];
    const float* ch_bn1_m = (const float*)d_in[28];
    const float* ch_bn1_v = (const float*)d_in[29];
    const float* ch_W2 = (const float*)d_in[30];
    const float* ch_b2 = (const float*)d_in[31];
    const float* ch_bn2_g = (const float*)d_in[32];
    const float* ch_bn2_b = (const float*)d_in[33];
    const float* ch_bn2_m = (const float*)d_in[34];
    const float* ch_bn2_v = (const float*)d_in[35];
    const float* ch_W3 = (const float*)d_in[36];
    const float* ch_b3 = (const float*)d_in[37];

    float* out = (float*)d_out;

    // workspace layout:
    // ints:   cnt[N] | rowstart[N] | cursor[N] | blocksums[512] | sorted_src[E]
    // floats: h1[N*H]
    // shorts: hb[N*H] | W1t[98304] | W2ft[49152] | W3ft[12288] | cntW1t[8192] | cntW2ft[1024]
    // floats: b2f[384] | b3f[144] | cntb2f[6]
    int* cnt = (int*)d_ws;
    int* rowstart = cnt + N_NODES;
    int* cursor = rowstart + N_NODES;
    int* blocksums = cursor + N_NODES;
    int* sorted_src = blocksums + 512;
    float* h1 = (float*)(sorted_src + N_EDGES);
    short* hb = (short*)(h1 + (size_t)N_NODES * H);
    short* W1t = hb + (size_t)N_NODES * H;
    short* W2ft = W1t + 98304;
    short* W3ft = W2ft + 49152;
    short* cntW1t = W3ft + 12288;
    short* cntW2ft = cntW1t + 8192;
    float* b2f = (float*)(cntW2ft + 1024);
    float* b3f = b2f + 384;
    float* cntb2f = b3f + 144;

    hipMemsetAsync(cnt, 0, N_NODES * sizeof(int), stream);

    k_prep<<<663, 256, 0, stream>>>(ch_W1, ch_W2, ch_W3,
                                    ch_bn1_g, ch_bn1_b, ch_bn1_m, ch_bn1_v,
                                    ch_bn2_g, ch_bn2_b, ch_bn2_m, ch_bn2_v,
                                    cnt_W1, cnt_W2,
                                    cnt_bn_g, cnt_bn_b, cnt_bn_m, cnt_bn_v,
                                    ch_b2, ch_b3, cnt_b2,
                                    W1t, W2ft, W3ft, cntW1t, cntW2ft,
                                    b2f, b3f, cntb2f);

    k_hist<<<N_EDGES / 256, 256, 0, stream>>>(ei, cnt);
    k_scan1<<<SCAN_BLOCKS, 256, 0, stream>>>(cnt, rowstart, blocksums);
    k_scan2<<<1, 512, 0, stream>>>(blocksums);
    k_scan3<<<SCAN_BLOCKS, 256, 0, stream>>>(rowstart, blocksums, cursor);
    k_fill<<<N_EDGES / 256, 256, 0, stream>>>(ei, cursor, sorted_src);

    k_agg1_layer1<<<N_NODES / 4, 256, 0, stream>>>(x, rowstart, cnt, sorted_src,
                                                   W1l, W1r, b1,
                                                   bn1_g, bn1_b, bn1_m, bn1_v, h1);
    k_agg2_layer2<<<N_NODES / 32, 256, 0, stream>>>(h1, rowstart, cnt, sorted_src,
                                                    W2l, W2r, b2,
                                                    bn2_g, bn2_b, bn2_m, bn2_v, hb);
    k_heads_mfma<<<(N_NODES + 63) / 64, 256, 0, stream>>>(
        hb, cnt_b1, ch_b1, W1t, W2ft, W3ft, cntW1t, cntW2ft,
        b2f, b3f, cntb2f, out);
}

// Round 4
// 790.114 us; speedup vs baseline: 4.4330x; 1.2254x over previous
//
#include <hip/hip_runtime.h>

#define N_NODES 100000
#define N_EDGES 1600000
#define F_IN 17
#define H 128
#define K_TYPES 6
#define MD 12
#define OUT_F 150
#define EPSL 1e-5f

#define SCAN_BLOCKS 391  // ceil(100000/256)

#define LDH 136  // LDS row stride (bf16) for 128-col tiles
#define LDZ 72   // LDS row stride (bf16) for 64-col tiles

typedef __attribute__((ext_vector_type(8))) short bf16x8;
typedef __attribute__((ext_vector_type(4))) float f32x4;
typedef __attribute__((ext_vector_type(4))) short s16x4;

static __device__ __forceinline__ short f2bf(float f) {
    union { float f; unsigned u; } v;
    v.f = f;
    unsigned r = (v.u + 0x7FFF + ((v.u >> 16) & 1)) >> 16;  // RNE
    return (short)r;
}

// ---------- CSR build: histogram ----------
__global__ __launch_bounds__(256) void k_hist(const int* __restrict__ ei,
                                              int* __restrict__ cnt) {
    int e = blockIdx.x * 256 + threadIdx.x;
    int dst = ei[N_EDGES + e];
    atomicAdd(&cnt[dst], 1);
}

// ---------- CSR build: scan stage 1 ----------
__global__ __launch_bounds__(256) void k_scan1(const int* __restrict__ cnt,
                                               int* __restrict__ rowstart,
                                               int* __restrict__ blocksums) {
    __shared__ int s[256];
    int tid = threadIdx.x;
    int i = blockIdx.x * 256 + tid;
    int v = (i < N_NODES) ? cnt[i] : 0;
    s[tid] = v;
    __syncthreads();
    for (int off = 1; off < 256; off <<= 1) {
        int t = (tid >= off) ? s[tid - off] : 0;
        __syncthreads();
        s[tid] += t;
        __syncthreads();
    }
    if (i < N_NODES) rowstart[i] = s[tid] - v;
    if (tid == 255) blocksums[blockIdx.x] = s[255];
}

// ---------- CSR build: scan stage 2 ----------
__global__ __launch_bounds__(512) void k_scan2(int* __restrict__ blocksums) {
    __shared__ int s[512];
    int t = threadIdx.x;
    int v0 = (t < SCAN_BLOCKS) ? blocksums[t] : 0;
    s[t] = v0;
    __syncthreads();
    for (int off = 1; off < 512; off <<= 1) {
        int tv = (t >= off) ? s[t - off] : 0;
        __syncthreads();
        s[t] += tv;
        __syncthreads();
    }
    if (t < SCAN_BLOCKS) blocksums[t] = s[t] - v0;
}

// ---------- CSR build: scan stage 3 ----------
__global__ __launch_bounds__(256) void k_scan3(int* __restrict__ rowstart,
                                               const int* __restrict__ blocksums,
                                               int* __restrict__ cursor) {
    int i = blockIdx.x * 256 + threadIdx.x;
    if (i < N_NODES) {
        int r = rowstart[i] + blocksums[blockIdx.x];
        rowstart[i] = r;
        cursor[i] = r;
    }
}

// ---------- CSR build: fill ----------
__global__ __launch_bounds__(256) void k_fill(const int* __restrict__ ei,
                                              int* __restrict__ cursor,
                                              int* __restrict__ sorted_src) {
    int e = blockIdx.x * 256 + threadIdx.x;
    int src = ei[e];
    int dst = ei[N_EDGES + e];
    int pos = atomicAdd(&cursor[dst], 1);
    sorted_src[pos] = src;
}

// ---------- prep: BN-fold + transpose + bf16-convert head weights ----------
__global__ __launch_bounds__(256) void k_prep(
    const float* __restrict__ ch_W1, const float* __restrict__ ch_W2,
    const float* __restrict__ ch_W3,
    const float* __restrict__ c1g, const float* __restrict__ c1b,
    const float* __restrict__ c1m, const float* __restrict__ c1v,
    const float* __restrict__ c2g, const float* __restrict__ c2b,
    const float* __restrict__ c2m, const float* __restrict__ c2v,
    const float* __restrict__ cnt_W1, const float* __restrict__ cnt_W2,
    const float* __restrict__ cbg, const float* __restrict__ cbb,
    const float* __restrict__ cbm, const float* __restrict__ cbv,
    const float* __restrict__ ch_b2, const float* __restrict__ ch_b3,
    const float* __restrict__ cnt_b2,
    short* __restrict__ W1t, short* __restrict__ W2ft, short* __restrict__ W3ft,
    short* __restrict__ cntW1t, short* __restrict__ cntW2ft,
    float* __restrict__ b2f, float* __restrict__ b3f, float* __restrict__ cntb2f) {
    int i = blockIdx.x * 256 + threadIdx.x;
    if (i < 98304) {  // W1t[k][o<128][d<128] <- ch_W1[k][d][o]
        int k = i >> 14, rem = i & 16383, o = rem >> 7, d = rem & 127;
        W1t[i] = f2bf(ch_W1[(k << 14) + (d << 7) + o]);
    } else if ((i -= 98304) < 49152) {  // W2ft[k][o<64][d<128] = A1[k][d]*ch_W2[k][d][o]
        int k = i >> 13, rem = i & 8191, o = rem >> 7, d = rem & 127;
        int ci = (k << 7) + d;
        float A1 = c1g[ci] * rsqrtf(c1v[ci] + EPSL);
        W2ft[i] = f2bf(ch_W2[(k << 13) + (d << 6) + o] * A1);
    } else if ((i -= 49152) < 12288) {  // W3ft[k][o<32][d<64], zero-pad o>=24
        int k = i >> 11, rem = i & 2047, o = rem >> 6, d = rem & 63;
        float val = 0.f;
        if (o < 24) {
            int ci = (k << 6) + d;
            float A2 = c2g[ci] * rsqrtf(c2v[ci] + EPSL);
            val = ch_W3[k * 1536 + d * 24 + o] * A2;
        }
        W3ft[i] = f2bf(val);
    } else if ((i -= 12288) < 8192) {  // cntW1t[o<64][d<128]
        int o = i >> 7, d = i & 127;
        cntW1t[i] = f2bf(cnt_W1[(d << 6) + o]);
    } else if ((i -= 8192) < 1024) {  // cntW2ft[o<16][d<64], zero-pad o>=6
        int o = i >> 6, d = i & 63;
        float val = 0.f;
        if (o < 6) val = cnt_W2[d * 6 + o] * (cbg[d] * rsqrtf(cbv[d] + EPSL));
        cntW2ft[i] = f2bf(val);
    } else if ((i -= 1024) < 384) {  // b2f[k][o<64]
        int k = i >> 6, o = i & 63;
        float s = ch_b2[i];
        for (int d = 0; d < 128; ++d) {
            int ci = (k << 7) + d;
            float A1 = c1g[ci] * rsqrtf(c1v[ci] + EPSL);
            float B1 = c1b[ci] - c1m[ci] * A1;
            s += B1 * ch_W2[(k << 13) + (d << 6) + o];
        }
        b2f[i] = s;
    } else if ((i -= 384) < 144) {  // b3f[k][o<24]
        int k = i / 24, o = i - k * 24;
        float s = ch_b3[i];
        for (int d = 0; d < 64; ++d) {
            int ci = (k << 6) + d;
            float A2 = c2g[ci] * rsqrtf(c2v[ci] + EPSL);
            float B2 = c2b[ci] - c2m[ci] * A2;
            s += B2 * ch_W3[k * 1536 + d * 24 + o];
        }
        b3f[i] = s;
    } else if ((i -= 144) < 6) {  // cntb2f[o<6]
        float s = cnt_b2[i];
        for (int d = 0; d < 64; ++d) {
            float Ac = cbg[d] * rsqrtf(cbv[d] + EPSL);
            float Bc = cbb[d] - cbm[d] * Ac;
            s += Bc * cnt_W2[d * 6 + i];
        }
        cntb2f[i] = s;
    }
}

// ---------- fused agg1 + layer1 ----------
__global__ __launch_bounds__(256) void k_agg1_layer1(
    const float* __restrict__ x, const int* __restrict__ rowstart,
    const int* __restrict__ cnt, const int* __restrict__ sorted_src,
    const float* __restrict__ W1l, const float* __restrict__ W1r,
    const float* __restrict__ b1,
    const float* __restrict__ g, const float* __restrict__ bb,
    const float* __restrict__ m, const float* __restrict__ v,
    float* __restrict__ h1) {
    int wave = threadIdx.x >> 6;
    int lane = threadIdx.x & 63;
    int n = blockIdx.x * 4 + wave;
    __shared__ float as[4][F_IN], xs[4][F_IN];

    int rs = rowstart[n];
    int d = cnt[n];
    if (lane < F_IN) {
        float acc = 0.f;
        for (int j = 0; j < d; ++j) {
            int src = sorted_src[rs + j];
            acc += x[(size_t)src * F_IN + lane];
        }
        float inv = 1.0f / fmaxf((float)d, 1.0f);
        as[wave][lane] = acc * inv;
        xs[wave][lane] = x[(size_t)n * F_IN + lane];
    }
    __syncthreads();

    float a0 = b1[lane], a1 = b1[lane + 64];
    for (int i = 0; i < F_IN; ++i) {
        float av = as[wave][i], xv = xs[wave][i];
        a0 += av * W1l[i * H + lane] + xv * W1r[i * H + lane];
        a1 += av * W1l[i * H + 64 + lane] + xv * W1r[i * H + 64 + lane];
    }
    int f0 = lane, f1 = lane + 64;
    float y0 = (a0 - m[f0]) * rsqrtf(v[f0] + EPSL) * g[f0] + bb[f0];
    float y1 = (a1 - m[f1]) * rsqrtf(v[f1] + EPSL) * g[f1] + bb[f1];
    h1[(size_t)n * H + f0] = fmaxf(y0, 0.f);
    h1[(size_t)n * H + f1] = fmaxf(y1, 0.f);
}

// ---------- fused agg2 + layer2, v2: paired-node float4 gather + 4x4 register-tiled GEMM ----------
__global__ __launch_bounds__(256) void k_agg2_layer2(
    const float* __restrict__ h1, const int* __restrict__ rowstart,
    const int* __restrict__ cnt, const int* __restrict__ sorted_src,
    const float* __restrict__ W2l, const float* __restrict__ W2r,
    const float* __restrict__ b2,
    const float* __restrict__ g, const float* __restrict__ bb,
    const float* __restrict__ m, const float* __restrict__ v,
    short* __restrict__ hb) {
    __shared__ float xs[32][256];  // [r][0:128]=agg_mean, [r][128:256]=root h1
    int t = threadIdx.x;
    int wave = t >> 6, lane = t & 63;
    int li = lane & 31;    // float4 index within the 128-float row
    int half = lane >> 5;  // which node of the pair
    int n0 = blockIdx.x * 32;
    const float4* h1v4 = (const float4*)h1;

    // gather: each wave handles 4 pairs of nodes; half-wave per node, float4/lane
    for (int q = 0; q < 4; ++q) {
        int r = wave * 8 + q * 2 + half;
        int n = n0 + r;
        int rs = rowstart[n];
        int d = cnt[n];
        float4 acc = {0.f, 0.f, 0.f, 0.f};
        for (int j = 0; j < d; j += 4) {  // divergent trip counts: exec-masked
            int rem = d - j;
            int s0 = sorted_src[rs + j];
            float4 v0 = h1v4[(size_t)s0 * 32 + li];
            float4 v1 = {0.f, 0.f, 0.f, 0.f}, v2 = v1, v3 = v1;
            if (rem > 1) { int s1 = sorted_src[rs + j + 1]; v1 = h1v4[(size_t)s1 * 32 + li]; }
            if (rem > 2) { int s2 = sorted_src[rs + j + 2]; v2 = h1v4[(size_t)s2 * 32 + li]; }
            if (rem > 3) { int s3 = sorted_src[rs + j + 3]; v3 = h1v4[(size_t)s3 * 32 + li]; }
            acc.x += (v0.x + v1.x) + (v2.x + v3.x);
            acc.y += (v0.y + v1.y) + (v2.y + v3.y);
            acc.z += (v0.z + v1.z) + (v2.z + v3.z);
            acc.w += (v0.w + v1.w) + (v2.w + v3.w);
        }
        float inv = 1.f / fmaxf((float)d, 1.f);
        acc.x *= inv; acc.y *= inv; acc.z *= inv; acc.w *= inv;
        *(float4*)&xs[r][4 * li] = acc;
        float4 rv = h1v4[(size_t)n * 32 + li];
        *(float4*)&xs[r][128 + 4 * li] = rv;
    }
    __syncthreads();

    // GEMM: 32x128 tile, K=128, 4 rows x 4 cols per thread
    int cg = t & 31;   // cols 4*cg .. 4*cg+3
    int rg = t >> 5;   // rows 4*rg .. 4*rg+3
    float4 acc2[4] = {};
    for (int k = 0; k < H; ++k) {
        float4 wl = *(const float4*)&W2l[k * H + 4 * cg];
        float4 wr = *(const float4*)&W2r[k * H + 4 * cg];
#pragma unroll
        for (int i = 0; i < 4; ++i) {
            float a = xs[4 * rg + i][k];
            float b = xs[4 * rg + i][128 + k];
            acc2[i].x += a * wl.x + b * wr.x;
            acc2[i].y += a * wl.y + b * wr.y;
            acc2[i].z += a * wl.z + b * wr.z;
            acc2[i].w += a * wl.w + b * wr.w;
        }
    }
    int c0 = 4 * cg;
    float4 bi = *(const float4*)&b2[c0];
    float4 vv = *(const float4*)&v[c0];
    float4 gg = *(const float4*)&g[c0];
    float4 mm = *(const float4*)&m[c0];
    float4 be = *(const float4*)&bb[c0];
    float scx = rsqrtf(vv.x + EPSL) * gg.x;
    float scy = rsqrtf(vv.y + EPSL) * gg.y;
    float scz = rsqrtf(vv.z + EPSL) * gg.z;
    float scw = rsqrtf(vv.w + EPSL) * gg.w;
#pragma unroll
    for (int i = 0; i < 4; ++i) {
        int n = n0 + 4 * rg + i;
        s16x4 o;
        o.x = f2bf(fmaxf((acc2[i].x + bi.x - mm.x) * scx + be.x, 0.f));
        o.y = f2bf(fmaxf((acc2[i].y + bi.y - mm.y) * scy + be.y, 0.f));
        o.z = f2bf(fmaxf((acc2[i].z + bi.z - mm.z) * scz + be.z, 0.f));
        o.w = f2bf(fmaxf((acc2[i].w + bi.w - mm.w) * scw + be.w, 0.f));
        *(s16x4*)&hb[(size_t)n * H + c0] = o;
    }
}

// ---------- heads via MFMA: 64 nodes/block, 4 waves ----------
__global__ __launch_bounds__(256) void k_heads_mfma(
    const short* __restrict__ hb,
    const float* __restrict__ cntb1, const float* __restrict__ ch_b1,
    const short* __restrict__ W1t, const short* __restrict__ W2ft,
    const short* __restrict__ W3ft, const short* __restrict__ cntW1t,
    const short* __restrict__ cntW2ft,
    const float* __restrict__ b2f, const float* __restrict__ b3f,
    const float* __restrict__ cntb2f,
    float* __restrict__ out) {
    __shared__ short hs[64 * LDH];
    __shared__ short z1[64 * LDH];
    __shared__ short z2[64 * LDZ];
    __shared__ short wst[64 * LDH];

    int t = threadIdx.x;
    int lane = t & 63, w = t >> 6;
    int lr = lane & 15, lk = lane >> 4;
    int n0 = blockIdx.x * 64;

#pragma unroll
    for (int it = 0; it < 4; ++it) {
        int idx = t * 8 + it * 2048;
        int r = idx >> 7, c = idx & 127;
        int n = n0 + r;
        if (n > N_NODES - 1) n = N_NODES - 1;
        *(int4*)&hs[r * LDH + c] = *(const int4*)&hb[(size_t)n * 128 + c];
    }
    __syncthreads();

    // ===== count head =====
#pragma unroll
    for (int it = 0; it < 4; ++it) {
        int idx = t * 8 + it * 2048;
        int r = idx >> 7, c = idx & 127;
        *(int4*)&wst[r * LDH + c] = *(const int4*)&cntW1t[idx];
    }
    __syncthreads();
    {
        f32x4 acc[4] = {};
#pragma unroll
        for (int ks = 0; ks < 4; ++ks) {
            bf16x8 a = *(bf16x8*)&hs[(16 * w + lr) * LDH + 32 * ks + lk * 8];
#pragma unroll
            for (int ct = 0; ct < 4; ++ct) {
                bf16x8 b = *(bf16x8*)&wst[(16 * ct + lr) * LDH + 32 * ks + lk * 8];
                acc[ct] = __builtin_amdgcn_mfma_f32_16x16x32_bf16(a, b, acc[ct], 0, 0, 0);
            }
        }
        __syncthreads();
#pragma unroll
        for (int ct = 0; ct < 4; ++ct) {
            int c = 16 * ct + lr;
            float bi = cntb1[c];
#pragma unroll
            for (int j = 0; j < 4; ++j) {
                int r = 16 * w + lk * 4 + j;
                z2[r * LDZ + c] = f2bf(fmaxf(acc[ct][j] + bi, 0.f));
            }
        }
    }
    {
        int idx = t * 8;
        if (idx < 16 * 64) {
            int r = idx >> 6, c = idx & 63;
            *(int4*)&wst[r * LDZ + c] = *(const int4*)&cntW2ft[idx];
        }
    }
    __syncthreads();
    {
        f32x4 acc = {};
#pragma unroll
        for (int ks = 0; ks < 2; ++ks) {
            bf16x8 a = *(bf16x8*)&z2[(16 * w + lr) * LDZ + 32 * ks + lk * 8];
            bf16x8 b = *(bf16x8*)&wst[lr * LDZ + 32 * ks + lk * 8];
            acc = __builtin_amdgcn_mfma_f32_16x16x32_bf16(a, b, acc, 0, 0, 0);
        }
        if (lr < 6) {
            float bi = cntb2f[lr];
#pragma unroll
            for (int j = 0; j < 4; ++j) {
                int r = 16 * w + lk * 4 + j, n = n0 + r;
                if (n < N_NODES) out[(size_t)n * OUT_F + lr] = acc[j] + bi;
            }
        }
    }
    __syncthreads();

    // ===== coord heads =====
    for (int k = 0; k < K_TYPES; ++k) {
        const short* W1k = W1t + k * 16384;
        for (int half = 0; half < 2; ++half) {
#pragma unroll
            for (int it = 0; it < 4; ++it) {
                int idx = t * 8 + it * 2048;
                int r = idx >> 7, c = idx & 127;
                *(int4*)&wst[r * LDH + c] = *(const int4*)&W1k[half * 8192 + idx];
            }
            __syncthreads();
            f32x4 acc[4] = {};
#pragma unroll
            for (int ks = 0; ks < 4; ++ks) {
                bf16x8 a = *(bf16x8*)&hs[(16 * w + lr) * LDH + 32 * ks + lk * 8];
#pragma unroll
                for (int ct = 0; ct < 4; ++ct) {
                    bf16x8 b = *(bf16x8*)&wst[(16 * ct + lr) * LDH + 32 * ks + lk * 8];
                    acc[ct] = __builtin_amdgcn_mfma_f32_16x16x32_bf16(a, b, acc[ct], 0, 0, 0);
                }
            }
            __syncthreads();
#pragma unroll
            for (int ct = 0; ct < 4; ++ct) {
                int c = 64 * half + 16 * ct + lr;
                float bi = ch_b1[k * 128 + c];
#pragma unroll
                for (int j = 0; j < 4; ++j) {
                    int r = 16 * w + lk * 4 + j;
                    z1[r * LDH + c] = f2bf(fmaxf(acc[ct][j] + bi, 0.f));
                }
            }
        }
#pragma unroll
        for (int it = 0; it < 4; ++it) {
            int idx = t * 8 + it * 2048;
            int r = idx >> 7, c = idx & 127;
            *(int4*)&wst[r * LDH + c] = *(const int4*)&W2ft[k * 8192 + idx];
        }
        __syncthreads();
        {
            f32x4 acc[4] = {};
#pragma unroll
            for (int ks = 0; ks < 4; ++ks) {
                bf16x8 a = *(bf16x8*)&z1[(16 * w + lr) * LDH + 32 * ks + lk * 8];
#pragma unroll
                for (int ct = 0; ct < 4; ++ct) {
                    bf16x8 b = *(bf16x8*)&wst[(16 * ct + lr) * LDH + 32 * ks + lk * 8];
                    acc[ct] = __builtin_amdgcn_mfma_f32_16x16x32_bf16(a, b, acc[ct], 0, 0, 0);
                }
            }
            __syncthreads();
#pragma unroll
            for (int ct = 0; ct < 4; ++ct) {
                int c = 16 * ct + lr;
                float bi = b2f[k * 64 + c];
#pragma unroll
                for (int j = 0; j < 4; ++j) {
                    int r = 16 * w + lk * 4 + j;
                    z2[r * LDZ + c] = f2bf(fmaxf(acc[ct][j] + bi, 0.f));
                }
            }
        }
        {
            int idx = t * 8;
            int r = idx >> 6, c = idx & 63;
            *(int4*)&wst[r * LDZ + c] = *(const int4*)&W3ft[k * 2048 + idx];
        }
        __syncthreads();
        {
            f32x4 acc[2] = {};
#pragma unroll
            for (int ks = 0; ks < 2; ++ks) {
                bf16x8 a = *(bf16x8*)&z2[(16 * w + lr) * LDZ + 32 * ks + lk * 8];
#pragma unroll
                for (int ct = 0; ct < 2; ++ct) {
                    bf16x8 b = *(bf16x8*)&wst[(16 * ct + lr) * LDZ + 32 * ks + lk * 8];
                    acc[ct] = __builtin_amdgcn_mfma_f32_16x16x32_bf16(a, b, acc[ct], 0, 0, 0);
                }
            }
#pragma unroll
            for (int ct = 0; ct < 2; ++ct) {
                int c = 16 * ct + lr;
                if (c < 24) {
                    float bi = b3f[k * 24 + c];
#pragma unroll
                    for (int j = 0; j < 4; ++j) {
                        int r = 16 * w + lk * 4 + j, n = n0 + r;
                        if (n < N_NODES)
                            out[(size_t)n * OUT_F + 6 + 24 * k + c] =
                                1.f / (1.f + expf(-(acc[ct][j] + bi)));
                    }
                }
            }
        }
        __syncthreads();
    }
}

extern "C" void kernel_launch(void* const* d_in, const int* in_sizes, int n_in,
                              void* d_out, int out_size, void* d_ws, size_t ws_size,
                              hipStream_t stream) {
    const float* x = (const float*)d_in[0];
    const int* ei = (const int*)d_in[1];
    const float* W1l = (const float*)d_in[2];
    const float* W1r = (const float*)d_in[3];
    const float* b1 = (const float*)d_in[4];
    const float* bn1_g = (const float*)d_in[5];
    const float* bn1_b = (const float*)d_in[6];
    const float* bn1_m = (const float*)d_in[7];
    const float* bn1_v = (const float*)d_in[8];
    const float* W2l = (const float*)d_in[9];
    const float* W2r = (const float*)d_in[10];
    const float* b2 = (const float*)d_in[11];
    const float* bn2_g = (const float*)d_in[12];
    const float* bn2_b = (const float*)d_in[13];
    const float* bn2_m = (const float*)d_in[14];
    const float* bn2_v = (const float*)d_in[15];
    const float* cnt_W1 = (const float*)d_in[16];
    const float* cnt_b1 = (const float*)d_in[17];
    const float* cnt_bn_g = (const float*)d_in[18];
    const float* cnt_bn_b = (const float*)d_in[19];
    const float* cnt_bn_m = (const float*)d_in[20];
    const float* cnt_bn_v = (const float*)d_in[21];
    const float* cnt_W2 = (const float*)d_in[22];
    const float* cnt_b2 = (const float*)d_in[23];
    const float* ch_W1 = (const float*)d_in[24];
    const float* ch_b1 = (const float*)d_in[25];
    const float* ch_bn1_g = (const float*)d_in[26];
    const float* ch_bn1_b = (const float*)d_in[27];
    const float* ch_bn1_m = (const float*)d_in[28];
    const float* ch_bn1_v = (const float*)d_in[29];
    const float* ch_W2 = (const float*)d_in[30];
    const float* ch_b2 = (const float*)d_in[31];
    const float* ch_bn2_g = (const float*)d_in[32];
    const float* ch_bn2_b = (const float*)d_in[33];
    const float* ch_bn2_m = (const float*)d_in[34];
    const float* ch_bn2_v = (const float*)d_in[35];
    const float* ch_W3 = (const float*)d_in[36];
    const float* ch_b3 = (const float*)d_in[37];

    float* out = (float*)d_out;

    int* cnt = (int*)d_ws;
    int* rowstart = cnt + N_NODES;
    int* cursor = rowstart + N_NODES;
    int* blocksums = cursor + N_NODES;
    int* sorted_src = blocksums + 512;
    float* h1 = (float*)(sorted_src + N_EDGES);
    short* hb = (short*)(h1 + (size_t)N_NODES * H);
    short* W1t = hb + (size_t)N_NODES * H;
    short* W2ft = W1t + 98304;
    short* W3ft = W2ft + 49152;
    short* cntW1t = W3ft + 12288;
    short* cntW2ft = cntW1t + 8192;
    float* b2f = (float*)(cntW2ft + 1024);
    float* b3f = b2f + 384;
    float* cntb2f = b3f + 144;

    hipMemsetAsync(cnt, 0, N_NODES * sizeof(int), stream);

    k_prep<<<663, 256, 0, stream>>>(ch_W1, ch_W2, ch_W3,
                                    ch_bn1_g, ch_bn1_b, ch_bn1_m, ch_bn1_v,
                                    ch_bn2_g, ch_bn2_b, ch_bn2_m, ch_bn2_v,
                                    cnt_W1, cnt_W2,
                                    cnt_bn_g, cnt_bn_b, cnt_bn_m, cnt_bn_v,
                                    ch_b2, ch_b3, cnt_b2,
                                    W1t, W2ft, W3ft, cntW1t, cntW2ft,
                                    b2f, b3f, cntb2f);

    k_hist<<<N_EDGES / 256, 256, 0, stream>>>(ei, cnt);
    k_scan1<<<SCAN_BLOCKS, 256, 0, stream>>>(cnt, rowstart, blocksums);
    k_scan2<<<1, 512, 0, stream>>>(blocksums);
    k_scan3<<<SCAN_BLOCKS, 256, 0, stream>>>(rowstart, blocksums, cursor);
    k_fill<<<N_EDGES / 256, 256, 0, stream>>>(ei, cursor, sorted_src);

    k_agg1_layer1<<<N_NODES / 4, 256, 0, stream>>>(x, rowstart, cnt, sorted_src,
                                                   W1l, W1r, b1,
                                                   bn1_g, bn1_b, bn1_m, bn1_v, h1);
    k_agg2_layer2<<<N_NODES / 32, 256, 0, stream>>>(h1, rowstart, cnt, sorted_src,
                                                    W2l, W2r, b2,
                                                    bn2_g, bn2_b, bn2_m, bn2_v, hb);
    k_heads_mfma<<<(N_NODES + 63) / 64, 256, 0, stream>>>(
        hb, cnt_b1, ch_b1, W1t, W2ft, W3ft, cntW1t, cntW2ft,
        b2f, b3f, cntb2f, out);
}